// Round 1
// baseline (290.216 us; speedup 1.0000x reference)
//
#include <hip/hip_runtime.h>
#include <math.h>

#define A_N 46035
#define B_N 32
#define M_N 64
#define SEGC 3
#define HW 245760            // 384*640
#define VEC_PER_PLANE 61440  // HW/4
#define BLOCKS_PER_PLANE 60
#define VEC_PER_BLOCK 1024   // VEC_PER_PLANE / BLOCKS_PER_PLANE
#define SEG_TOTAL 23592960   // B*SEGC*HW

// ws layout (doubles):
// [0..31]   cls_sum per image
// [32..63]  reg_sum per image
// [64..95]  num_pos per image
// [96..98]  inter[c]
// [99..101] fp[c]
// [102..104] fn[c]
// [105]     focal_sum
#define WS_N 106

__device__ __forceinline__ double waveRed(double v) {
    for (int o = 32; o; o >>= 1) v += __shfl_down(v, o, 64);
    return v;
}

__global__ void zero_ws_kernel(double* ws) {
    int i = threadIdx.x;
    if (i < WS_N) ws[i] = 0.0;
}

__global__ __launch_bounds__(256) void det_kernel(
    const float* __restrict__ cls,   // [B,A,1]
    const float* __restrict__ reg,   // [B,A,4]
    const float* __restrict__ anc,   // [A,4] (y1,x1,y2,x2)
    const float* __restrict__ ann,   // [B,M,5] (x1,y1,x2,y2,label)
    double* __restrict__ ws)
{
    const int b = blockIdx.y;
    const int a = blockIdx.x * 256 + threadIdx.x;

    __shared__ float sann[M_N * 5];
    for (int i = threadIdx.x; i < M_N * 5; i += 256)
        sann[i] = ann[b * M_N * 5 + i];
    __syncthreads();

    double cls_c = 0.0, reg_c = 0.0, pos_c = 0.0;

    if (a < A_N) {
        const float4 av = *reinterpret_cast<const float4*>(&anc[a * 4]);
        const float ay1 = av.x, ax1 = av.y, ay2 = av.z, ax2 = av.w;
        const float aw = ax2 - ax1;       // anchor[:,3]-anchor[:,1]
        const float ah = ay2 - ay1;       // anchor[:,2]-anchor[:,0]
        const float acx = ax1 + 0.5f * aw;
        const float acy = ay1 + 0.5f * ah;
        const float aarea = ah * aw;      // (a2-a0)*(a3-a1)

        float best = -__builtin_inff();
        int barg = 0;
        #pragma unroll 8
        for (int m = 0; m < M_N; ++m) {
            const float bx1 = sann[m * 5 + 0];
            const float by1 = sann[m * 5 + 1];
            const float bx2 = sann[m * 5 + 2];
            const float by2 = sann[m * 5 + 3];
            const float lbl = sann[m * 5 + 4];
            float v;
            if (lbl == -1.0f) {
                v = -1.0f;
            } else {
                const float barea = (bx2 - bx1) * (by2 - by1);
                float iw = fminf(ax2, bx2) - fmaxf(ax1, bx1);
                float ih = fminf(ay2, by2) - fmaxf(ay1, by1);
                iw = fmaxf(iw, 0.0f);
                ih = fmaxf(ih, 0.0f);
                const float ua = fmaxf(aarea + barea - iw * ih, 1e-8f);
                v = iw * ih / ua;
            }
            if (v > best) { best = v; barg = m; }  // first-max tiebreak like argmax
        }

        const float gx1 = sann[barg * 5 + 0];
        const float gy1 = sann[barg * 5 + 1];
        const float gx2 = sann[barg * 5 + 2];
        const float gy2 = sann[barg * 5 + 3];
        const float glb = sann[barg * 5 + 4];

        const float big_area = (gx2 - gx1) * (gy2 - gy1);
        const bool pos = (big_area > 100.0f) ? (best >= 0.5f) : (best >= 0.15f);
        pos_c = pos ? 1.0 : 0.0;

        // focal classification (C=1)
        float p = cls[b * A_N + a];
        p = fminf(fmaxf(p, 1e-4f), 1.0f - 1e-4f);
        const bool t1 = pos && ((int)glb == 0);   // one_hot(label,1)*posf == 1
        const float af = t1 ? 0.25f : 0.75f;
        const float fw = t1 ? (1.0f - p) : p;
        const float bce = t1 ? (-logf(p)) : (-logf(1.0f - p));
        cls_c = (double)(af * fw * fw * bce);

        // regression smooth-L1 (only positives contribute)
        if (pos) {
            const float gw0 = gx2 - gx1;
            const float gh0 = gy2 - gy1;
            const float gcx = gx1 + 0.5f * gw0;   // centers from UNclamped sizes
            const float gcy = gy1 + 0.5f * gh0;
            const float gw = fmaxf(gw0, 1.0f);
            const float gh = fmaxf(gh0, 1.0f);
            const float tdx = (gcx - acx) / aw;
            const float tdy = (gcy - acy) / ah;
            const float tdw = logf(gw / aw);
            const float tdh = logf(gh / ah);
            float tgt0 = tdy, tgt1 = tdx, tgt2 = tdh, tgt3 = tdw;

            const float4 rv = *reinterpret_cast<const float4*>(&reg[(size_t)(b * A_N + a) * 4]);
            float d, rl, s = 0.0f;
            d = fabsf(tgt0 - rv.x); rl = (d <= 1.0f/9.0f) ? 4.5f*d*d : d - 0.5f/9.0f; s += rl;
            d = fabsf(tgt1 - rv.y); rl = (d <= 1.0f/9.0f) ? 4.5f*d*d : d - 0.5f/9.0f; s += rl;
            d = fabsf(tgt2 - rv.z); rl = (d <= 1.0f/9.0f) ? 4.5f*d*d : d - 0.5f/9.0f; s += rl;
            d = fabsf(tgt3 - rv.w); rl = (d <= 1.0f/9.0f) ? 4.5f*d*d : d - 0.5f/9.0f; s += rl;
            reg_c = (double)s;
        }
    }

    // block reduce 3 doubles -> one atomic each per block
    __shared__ double sred[3][4];
    const int wid = threadIdx.x >> 6, lane = threadIdx.x & 63;
    cls_c = waveRed(cls_c);
    reg_c = waveRed(reg_c);
    pos_c = waveRed(pos_c);
    if (lane == 0) { sred[0][wid] = cls_c; sred[1][wid] = reg_c; sred[2][wid] = pos_c; }
    __syncthreads();
    if (threadIdx.x == 0) {
        double c = 0, r = 0, pp = 0;
        for (int w = 0; w < 4; ++w) { c += sred[0][w]; r += sred[1][w]; pp += sred[2][w]; }
        atomicAdd(&ws[b], c);
        atomicAdd(&ws[32 + b], r);
        atomicAdd(&ws[64 + b], pp);
    }
}

__global__ __launch_bounds__(256) void seg_kernel(
    const float* __restrict__ pred,   // [B,3,H,W] logits
    const float* __restrict__ annot,  // [B,3,H,W] one-hot
    double* __restrict__ ws)
{
    const int blk = blockIdx.x;                 // 0..5759
    const int plane = blk / BLOCKS_PER_PLANE;   // 0..95  (wave-uniform)
    const int c = plane % SEGC;
    const long base = (long)plane * HW + (long)(blk % BLOCKS_PER_PLANE) * (VEC_PER_BLOCK * 4);

    double inter = 0.0, fpv = 0.0, fnv = 0.0, foc = 0.0;

    #pragma unroll
    for (int it = 0; it < VEC_PER_BLOCK / 256; ++it) {   // 4 iters
        const long idx = base + (long)(it * 256 + threadIdx.x) * 4;
        const float4 yp = *reinterpret_cast<const float4*>(&pred[idx]);
        const float4 yt = *reinterpret_cast<const float4*>(&annot[idx]);

        const float px[4] = { yp.x, yp.y, yp.z, yp.w };
        const float tx[4] = { yt.x, yt.y, yt.z, yt.w };
        #pragma unroll
        for (int j = 0; j < 4; ++j) {
            const float x = px[j], y = tx[j];
            inter += (double)(x * y);
            fpv   += (double)(x * (1.0f - y));
            fnv   += (double)((1.0f - x) * y);
            // focal: logpt = logaddexp(0,x) - x*y (stable)
            const float logpt = fmaxf(x, 0.0f) + log1pf(expf(-fabsf(x))) - x * y;
            const float pt = expf(-logpt);
            const float w = 0.25f * y + 0.75f * (1.0f - y);
            const float om = 1.0f - pt;
            foc += (double)(om * om * logpt * w);
        }
    }

    __shared__ double sred[4][4];
    const int wid = threadIdx.x >> 6, lane = threadIdx.x & 63;
    inter = waveRed(inter);
    fpv   = waveRed(fpv);
    fnv   = waveRed(fnv);
    foc   = waveRed(foc);
    if (lane == 0) { sred[0][wid] = inter; sred[1][wid] = fpv; sred[2][wid] = fnv; sred[3][wid] = foc; }
    __syncthreads();
    if (threadIdx.x == 0) {
        double a = 0, b2 = 0, cc = 0, dd = 0;
        for (int w = 0; w < 4; ++w) { a += sred[0][w]; b2 += sred[1][w]; cc += sred[2][w]; dd += sred[3][w]; }
        atomicAdd(&ws[96 + c], a);
        atomicAdd(&ws[99 + c], b2);
        atomicAdd(&ws[102 + c], cc);
        atomicAdd(&ws[105], dd);
    }
}

__global__ void fin_kernel(const double* __restrict__ ws, float* __restrict__ out) {
    if (threadIdx.x == 0) {
        double clsm = 0.0, regm = 0.0;
        for (int b = 0; b < B_N; ++b) {
            const double np_ = ws[64 + b];
            const double mnp = fmax(np_, 1.0);
            clsm += ws[b] / mnp;
            regm += (np_ > 0.0) ? ws[32 + b] / (4.0 * mnp) : 0.0;
        }
        clsm /= (double)B_N;
        regm = regm / (double)B_N * 50.0;

        double tsum = 0.0;
        for (int c = 0; c < SEGC; ++c) {
            const double inter = ws[96 + c];
            const double fpv = ws[99 + c];
            const double fnv = ws[102 + c];
            const double denom = fmax(inter + 0.7 * fpv + 0.3 * fnv, 1e-7);
            const double score = inter / denom;
            const double ytsum = inter + fnv;          // sum of yt for class c
            const double mask = (ytsum > 0.0) ? 1.0 : 0.0;
            tsum += (1.0 - score) * mask;
        }
        const double tv = pow(tsum / 3.0, 4.0 / 3.0);
        const double focm = ws[105] / (double)SEG_TOTAL;

        out[0] = (float)clsm;
        out[1] = (float)regm;
        out[2] = (float)(tv + focm);
    }
}

extern "C" void kernel_launch(void* const* d_in, const int* in_sizes, int n_in,
                              void* d_out, int out_size, void* d_ws, size_t ws_size,
                              hipStream_t stream) {
    const float* cls    = (const float*)d_in[0];  // [B,A,1]
    const float* reg    = (const float*)d_in[1];  // [B,A,4]
    const float* anc    = (const float*)d_in[2];  // [1,A,4]
    const float* ann    = (const float*)d_in[3];  // [B,M,5]
    const float* seg    = (const float*)d_in[4];  // [B,3,H,W]
    const float* segann = (const float*)d_in[5];  // [B,3,H,W]
    double* ws = (double*)d_ws;
    float* out = (float*)d_out;

    zero_ws_kernel<<<1, 128, 0, stream>>>(ws);

    const int ablocks = (A_N + 255) / 256;  // 180
    det_kernel<<<dim3(ablocks, B_N), 256, 0, stream>>>(cls, reg, anc, ann, ws);

    seg_kernel<<<B_N * SEGC * BLOCKS_PER_PLANE, 256, 0, stream>>>(seg, segann, ws);

    fin_kernel<<<1, 64, 0, stream>>>(ws, out);
}

// Round 2
// 280.017 us; speedup vs baseline: 1.0364x; 1.0364x over previous
//
#include <hip/hip_runtime.h>
#include <math.h>

#define A_N 46035
#define B_N 32
#define M_N 64
#define SEGC 3
#define HW 245760            // 384*640
#define BLOCKS_PER_PLANE 60
#define VEC_PER_BLOCK 1024   // float4 per block
#define SEG_TOTAL 23592960   // B*SEGC*HW
#define DET_K 8              // anchors per thread

// ws layout (doubles):
// [0..31]   cls_sum per image
// [32..63]  reg_sum per image
// [64..95]  num_pos per image
// [96..98]  inter[c]  (sum x*y)
// [99..101] fp[c]     (sum x*(1-y))
// [102..104] ycnt[c]  (sum y)  -> fn = ycnt - inter
// [105]     focal_sum
#define WS_N 106

__device__ __forceinline__ double waveRed(double v) {
    for (int o = 32; o; o >>= 1) v += __shfl_down(v, o, 64);
    return v;
}

__global__ void zero_ws_kernel(double* ws) {
    int i = threadIdx.x;
    if (i < WS_N) ws[i] = 0.0;
}

__global__ __launch_bounds__(256) void det_kernel(
    const float* __restrict__ cls,   // [B,A,1]
    const float* __restrict__ reg,   // [B,A,4]
    const float* __restrict__ anc,   // [A,4] (y1,x1,y2,x2)
    const float* __restrict__ ann,   // [B,M,5] (x1,y1,x2,y2,label)
    double* __restrict__ ws)
{
    const int b = blockIdx.y;
    const int tid = threadIdx.x;
    const int a_base = blockIdx.x * (256 * DET_K) + tid;   // thread's anchors: a_base + k*256

    __shared__ float4 sbox[M_N];   // x1,y1,x2,y2
    __shared__ float2 sal[M_N];    // area, label
    if (tid < M_N) {
        const float* p = &ann[(b * M_N + tid) * 5];
        const float x1 = p[0], y1 = p[1], x2 = p[2], y2 = p[3], lb = p[4];
        sbox[tid] = make_float4(x1, y1, x2, y2);
        sal[tid] = make_float2((x2 - x1) * (y2 - y1), lb);
    }
    __syncthreads();

    float ax1[DET_K], ay1[DET_K], ax2[DET_K], ay2[DET_K], aarea[DET_K];
    float best[DET_K];
    int barg[DET_K];
    bool act[DET_K];

    #pragma unroll
    for (int k = 0; k < DET_K; ++k) {
        int a = a_base + k * 256;
        act[k] = a < A_N;
        const int al = act[k] ? a : (A_N - 1);
        const float4 av = *reinterpret_cast<const float4*>(&anc[al * 4]);
        ay1[k] = av.x; ax1[k] = av.y; ay2[k] = av.z; ax2[k] = av.w;
        aarea[k] = (av.z - av.x) * (av.w - av.y);
        best[k] = -__builtin_inff();
        barg[k] = 0;
    }

    #pragma unroll 2
    for (int m = 0; m < M_N; ++m) {
        const float4 bb = sbox[m];
        const float ba = sal[m].x;
        #pragma unroll
        for (int k = 0; k < DET_K; ++k) {
            const float iw = fminf(ax2[k], bb.z) - fmaxf(ax1[k], bb.x);
            const float ih = fminf(ay2[k], bb.w) - fmaxf(ay1[k], bb.y);
            const float inter = fmaxf(iw, 0.0f) * fmaxf(ih, 0.0f);
            const float ua = fmaxf(aarea[k] + ba - inter, 1e-8f);
            const float v = inter * __builtin_amdgcn_rcpf(ua);
            const bool upd = v > best[k];
            best[k] = upd ? v : best[k];
            barg[k] = upd ? m : barg[k];
        }
    }

    float cls_f = 0.0f, reg_f = 0.0f;
    int pos_i = 0;

    #pragma unroll
    for (int k = 0; k < DET_K; ++k) {
        if (!act[k]) continue;
        const int a = a_base + k * 256;
        const float4 g = sbox[barg[k]];
        const float2 al2 = sal[barg[k]];

        const bool big = al2.x > 100.0f;     // (x2-x1)*(y2-y1) > 100
        const bool pos = big ? (best[k] >= 0.5f) : (best[k] >= 0.15f);
        pos_i += pos ? 1 : 0;

        // focal classification (C=1); valid labels are 0 -> one-hot channel 0
        float p = cls[b * A_N + a];
        p = fminf(fmaxf(p, 1e-4f), 1.0f - 1e-4f);
        const bool t1 = pos && ((int)al2.y == 0);
        const float af = t1 ? 0.25f : 0.75f;
        const float fw = t1 ? (1.0f - p) : p;
        const float bce = t1 ? (-logf(p)) : (-logf(1.0f - p));
        cls_f += af * fw * fw * bce;

        if (pos) {
            const float aw = ax2[k] - ax1[k];
            const float ah = ay2[k] - ay1[k];
            const float acx = ax1[k] + 0.5f * aw;
            const float acy = ay1[k] + 0.5f * ah;
            const float gw0 = g.z - g.x;
            const float gh0 = g.w - g.y;
            const float gcx = g.x + 0.5f * gw0;   // centers from UNclamped sizes
            const float gcy = g.y + 0.5f * gh0;
            const float gw = fmaxf(gw0, 1.0f);
            const float gh = fmaxf(gh0, 1.0f);
            const float t0 = (gcy - acy) / ah;    // tdy
            const float t1r = (gcx - acx) / aw;   // tdx
            const float t2 = logf(gh / ah);       // tdh
            const float t3 = logf(gw / aw);       // tdw

            const float4 rv = *reinterpret_cast<const float4*>(&reg[(size_t)(b * A_N + a) * 4]);
            float d, rl, s = 0.0f;
            d = fabsf(t0 - rv.x);  rl = (d <= 1.0f/9.0f) ? 4.5f*d*d : d - 0.5f/9.0f; s += rl;
            d = fabsf(t1r - rv.y); rl = (d <= 1.0f/9.0f) ? 4.5f*d*d : d - 0.5f/9.0f; s += rl;
            d = fabsf(t2 - rv.z);  rl = (d <= 1.0f/9.0f) ? 4.5f*d*d : d - 0.5f/9.0f; s += rl;
            d = fabsf(t3 - rv.w);  rl = (d <= 1.0f/9.0f) ? 4.5f*d*d : d - 0.5f/9.0f; s += rl;
            reg_f += s;
        }
    }

    double cls_c = (double)cls_f, reg_c = (double)reg_f, pos_c = (double)pos_i;

    __shared__ double sred[3][4];
    const int wid = threadIdx.x >> 6, lane = threadIdx.x & 63;
    cls_c = waveRed(cls_c);
    reg_c = waveRed(reg_c);
    pos_c = waveRed(pos_c);
    if (lane == 0) { sred[0][wid] = cls_c; sred[1][wid] = reg_c; sred[2][wid] = pos_c; }
    __syncthreads();
    if (threadIdx.x == 0) {
        double c = 0, r = 0, pp = 0;
        for (int w = 0; w < 4; ++w) { c += sred[0][w]; r += sred[1][w]; pp += sred[2][w]; }
        atomicAdd(&ws[b], c);
        atomicAdd(&ws[32 + b], r);
        atomicAdd(&ws[64 + b], pp);
    }
}

__global__ __launch_bounds__(256) void seg_kernel(
    const float* __restrict__ pred,   // [B,3,H,W] logits
    const float* __restrict__ annot,  // [B,3,H,W] one-hot (exact 0/1)
    double* __restrict__ ws)
{
    const int blk = blockIdx.x;                 // 0..5759
    const int plane = blk / BLOCKS_PER_PLANE;   // 0..95  (wave-uniform)
    const int c = plane % SEGC;
    const long base = (long)plane * HW + (long)(blk % BLOCKS_PER_PLANE) * (VEC_PER_BLOCK * 4);

    float sxy = 0.0f, sx0 = 0.0f, syv = 0.0f, foc = 0.0f;

    #pragma unroll
    for (int it = 0; it < VEC_PER_BLOCK / 256; ++it) {   // 4 iters, 16 elems/thread
        const long idx = base + (long)(it * 256 + threadIdx.x) * 4;
        const float4 yp = *reinterpret_cast<const float4*>(&pred[idx]);
        const float4 yt = *reinterpret_cast<const float4*>(&annot[idx]);

        const float px[4] = { yp.x, yp.y, yp.z, yp.w };
        const float tx[4] = { yt.x, yt.y, yt.z, yt.w };
        #pragma unroll
        for (int j = 0; j < 4; ++j) {
            const float x = px[j], y = tx[j];
            const bool sel = y > 0.5f;
            sxy = fmaf(x, y, sxy);
            sx0 = fmaf(x, 1.0f - y, sx0);
            syv += y;
            // focal: s = (2y-1)x; t=e^{-s}; logpt=log(1+t); 1-pt = t/(1+t)
            const float s = sel ? x : -x;
            const float t = __expf(-s);
            const float u = 1.0f + t;
            const float r = __builtin_amdgcn_rcpf(u);
            const float omp = t * r;
            const float logpt = __logf(u);
            const float w = sel ? 0.25f : 0.75f;
            foc += omp * omp * logpt * w;
        }
    }

    double inter = (double)sxy, fpv = (double)sx0, ycv = (double)syv, fo = (double)foc;

    __shared__ double sred[4][4];
    const int wid = threadIdx.x >> 6, lane = threadIdx.x & 63;
    inter = waveRed(inter);
    fpv   = waveRed(fpv);
    ycv   = waveRed(ycv);
    fo    = waveRed(fo);
    if (lane == 0) { sred[0][wid] = inter; sred[1][wid] = fpv; sred[2][wid] = ycv; sred[3][wid] = fo; }
    __syncthreads();
    if (threadIdx.x == 0) {
        double a = 0, b2 = 0, cc = 0, dd = 0;
        for (int w = 0; w < 4; ++w) { a += sred[0][w]; b2 += sred[1][w]; cc += sred[2][w]; dd += sred[3][w]; }
        atomicAdd(&ws[96 + c], a);
        atomicAdd(&ws[99 + c], b2);
        atomicAdd(&ws[102 + c], cc);
        atomicAdd(&ws[105], dd);
    }
}

__global__ void fin_kernel(const double* __restrict__ ws, float* __restrict__ out) {
    if (threadIdx.x == 0) {
        double clsm = 0.0, regm = 0.0;
        for (int b = 0; b < B_N; ++b) {
            const double np_ = ws[64 + b];
            const double mnp = fmax(np_, 1.0);
            clsm += ws[b] / mnp;
            regm += (np_ > 0.0) ? ws[32 + b] / (4.0 * mnp) : 0.0;
        }
        clsm /= (double)B_N;
        regm = regm / (double)B_N * 50.0;

        double tsum = 0.0;
        for (int c = 0; c < SEGC; ++c) {
            const double inter = ws[96 + c];
            const double fpv = ws[99 + c];
            const double ycnt = ws[102 + c];
            const double fnv = ycnt - inter;           // sum (1-x)*y
            const double denom = fmax(inter + 0.7 * fpv + 0.3 * fnv, 1e-7);
            const double score = inter / denom;
            const double mask = (ycnt > 0.0) ? 1.0 : 0.0;
            tsum += (1.0 - score) * mask;
        }
        const double tv = pow(tsum / 3.0, 4.0 / 3.0);
        const double focm = ws[105] / (double)SEG_TOTAL;

        out[0] = (float)clsm;
        out[1] = (float)regm;
        out[2] = (float)(tv + focm);
    }
}

extern "C" void kernel_launch(void* const* d_in, const int* in_sizes, int n_in,
                              void* d_out, int out_size, void* d_ws, size_t ws_size,
                              hipStream_t stream) {
    const float* cls    = (const float*)d_in[0];  // [B,A,1]
    const float* reg    = (const float*)d_in[1];  // [B,A,4]
    const float* anc    = (const float*)d_in[2];  // [1,A,4]
    const float* ann    = (const float*)d_in[3];  // [B,M,5]
    const float* seg    = (const float*)d_in[4];  // [B,3,H,W]
    const float* segann = (const float*)d_in[5];  // [B,3,H,W]
    double* ws = (double*)d_ws;
    float* out = (float*)d_out;

    zero_ws_kernel<<<1, 128, 0, stream>>>(ws);

    const int ablocks = (A_N + 256 * DET_K - 1) / (256 * DET_K);  // 23
    det_kernel<<<dim3(ablocks, B_N), 256, 0, stream>>>(cls, reg, anc, ann, ws);

    seg_kernel<<<B_N * SEGC * BLOCKS_PER_PLANE, 256, 0, stream>>>(seg, segann, ws);

    fin_kernel<<<1, 64, 0, stream>>>(ws, out);
}

// Round 3
// 104.910 us; speedup vs baseline: 2.7663x; 2.6691x over previous
//
#include <hip/hip_runtime.h>
#include <math.h>

#define A_N 46035
#define B_N 32
#define M_N 64
#define SEGC 3
#define HW 245760            // 384*640
#define HW4 61440            // HW/4
#define NBP 15               // seg blocks per plane
#define SEG_BLOCKS (B_N * SEGC * NBP)   // 1440
#define SEG_TOTAL 23592960   // B*SEGC*HW
#define DET_K 8              // anchors per thread
#define ABLK 23              // ceil(A_N / (256*DET_K))

// ws layout (doubles), all slots written unconditionally each call:
// det partials: [3][B_N][ABLK]  (q=0 cls, q=1 reg, q=2 pos)      = 2208
// seg partials: [SEGC][4][480]  (q=0 inter, 1 fp, 2 ycnt, 3 foc) = 5760
#define DET_WS 2208
#define SEG_WS_OFF DET_WS
#define SEG_S 480            // B_N * NBP partials per (c,q)

__device__ __forceinline__ double waveRed(double v) {
    for (int o = 32; o; o >>= 1) v += __shfl_down(v, o, 64);
    return v;
}

__global__ __launch_bounds__(256) void det_kernel(
    const float* __restrict__ cls,   // [B,A,1]
    const float* __restrict__ reg,   // [B,A,4]
    const float* __restrict__ anc,   // [A,4] (y1,x1,y2,x2)
    const float* __restrict__ ann,   // [B,M,5] (x1,y1,x2,y2,label)
    double* __restrict__ ws)
{
    const int b = blockIdx.y;
    const int bx = blockIdx.x;
    const int tid = threadIdx.x;
    const int a_base = bx * (256 * DET_K) + tid;

    __shared__ float4 sbox[M_N];   // x1,y1,x2,y2
    __shared__ float2 sal[M_N];    // area, label
    if (tid < M_N) {
        const float* p = &ann[(b * M_N + tid) * 5];
        const float x1 = p[0], y1 = p[1], x2 = p[2], y2 = p[3], lb = p[4];
        sbox[tid] = make_float4(x1, y1, x2, y2);
        sal[tid] = make_float2((x2 - x1) * (y2 - y1), lb);
    }
    __syncthreads();

    float ax1[DET_K], ay1[DET_K], ax2[DET_K], ay2[DET_K], aarea[DET_K];
    float best[DET_K];
    int barg[DET_K];
    bool act[DET_K];

    #pragma unroll
    for (int k = 0; k < DET_K; ++k) {
        int a = a_base + k * 256;
        act[k] = a < A_N;
        const int al = act[k] ? a : (A_N - 1);
        const float4 av = *reinterpret_cast<const float4*>(&anc[al * 4]);
        ay1[k] = av.x; ax1[k] = av.y; ay2[k] = av.z; ax2[k] = av.w;
        aarea[k] = (av.z - av.x) * (av.w - av.y);
        best[k] = -__builtin_inff();
        barg[k] = 0;
    }

    #pragma unroll 2
    for (int m = 0; m < M_N; ++m) {
        const float4 bb = sbox[m];
        const float ba = sal[m].x;
        #pragma unroll
        for (int k = 0; k < DET_K; ++k) {
            const float iw = fminf(ax2[k], bb.z) - fmaxf(ax1[k], bb.x);
            const float ih = fminf(ay2[k], bb.w) - fmaxf(ay1[k], bb.y);
            const float inter = fmaxf(iw, 0.0f) * fmaxf(ih, 0.0f);
            const float ua = fmaxf(aarea[k] + ba - inter, 1e-8f);
            const float v = inter * __builtin_amdgcn_rcpf(ua);
            const bool upd = v > best[k];
            best[k] = upd ? v : best[k];
            barg[k] = upd ? m : barg[k];
        }
    }

    float cls_f = 0.0f, reg_f = 0.0f;
    int pos_i = 0;

    #pragma unroll
    for (int k = 0; k < DET_K; ++k) {
        if (!act[k]) continue;
        const int a = a_base + k * 256;
        const float4 g = sbox[barg[k]];
        const float2 al2 = sal[barg[k]];

        const bool big = al2.x > 100.0f;
        const bool pos = big ? (best[k] >= 0.5f) : (best[k] >= 0.15f);
        pos_i += pos ? 1 : 0;

        float p = cls[b * A_N + a];
        p = fminf(fmaxf(p, 1e-4f), 1.0f - 1e-4f);
        const bool t1 = pos && ((int)al2.y == 0);
        const float af = t1 ? 0.25f : 0.75f;
        const float fw = t1 ? (1.0f - p) : p;
        const float bce = t1 ? (-logf(p)) : (-logf(1.0f - p));
        cls_f += af * fw * fw * bce;

        if (pos) {
            const float aw = ax2[k] - ax1[k];
            const float ah = ay2[k] - ay1[k];
            const float acx = ax1[k] + 0.5f * aw;
            const float acy = ay1[k] + 0.5f * ah;
            const float gw0 = g.z - g.x;
            const float gh0 = g.w - g.y;
            const float gcx = g.x + 0.5f * gw0;   // centers from UNclamped sizes
            const float gcy = g.y + 0.5f * gh0;
            const float gw = fmaxf(gw0, 1.0f);
            const float gh = fmaxf(gh0, 1.0f);
            const float t0 = (gcy - acy) / ah;    // tdy
            const float t1r = (gcx - acx) / aw;   // tdx
            const float t2 = logf(gh / ah);       // tdh
            const float t3 = logf(gw / aw);       // tdw

            const float4 rv = *reinterpret_cast<const float4*>(&reg[(size_t)(b * A_N + a) * 4]);
            float d, rl, s = 0.0f;
            d = fabsf(t0 - rv.x);  rl = (d <= 1.0f/9.0f) ? 4.5f*d*d : d - 0.5f/9.0f; s += rl;
            d = fabsf(t1r - rv.y); rl = (d <= 1.0f/9.0f) ? 4.5f*d*d : d - 0.5f/9.0f; s += rl;
            d = fabsf(t2 - rv.z);  rl = (d <= 1.0f/9.0f) ? 4.5f*d*d : d - 0.5f/9.0f; s += rl;
            d = fabsf(t3 - rv.w);  rl = (d <= 1.0f/9.0f) ? 4.5f*d*d : d - 0.5f/9.0f; s += rl;
            reg_f += s;
        }
    }

    double cls_c = (double)cls_f, reg_c = (double)reg_f, pos_c = (double)pos_i;

    __shared__ double sred[3][4];
    const int wid = threadIdx.x >> 6, lane = threadIdx.x & 63;
    cls_c = waveRed(cls_c);
    reg_c = waveRed(reg_c);
    pos_c = waveRed(pos_c);
    if (lane == 0) { sred[0][wid] = cls_c; sred[1][wid] = reg_c; sred[2][wid] = pos_c; }
    __syncthreads();
    if (threadIdx.x == 0) {
        double c = 0, r = 0, pp = 0;
        for (int w = 0; w < 4; ++w) { c += sred[0][w]; r += sred[1][w]; pp += sred[2][w]; }
        // plain stores: one unique slot per (quantity, image, block)
        ws[0 * (B_N * ABLK) + b * ABLK + bx] = c;
        ws[1 * (B_N * ABLK) + b * ABLK + bx] = r;
        ws[2 * (B_N * ABLK) + b * ABLK + bx] = pp;
    }
}

__global__ __launch_bounds__(256) void seg_kernel(
    const float* __restrict__ pred,   // [B,3,H,W] logits
    const float* __restrict__ annot,  // [B,3,H,W] one-hot (exact 0/1)
    double* __restrict__ ws)
{
    const int sblk = blockIdx.x;             // 0..1439
    const int plane = sblk / NBP;            // 0..95 (wave-uniform)
    const int bp = sblk % NBP;
    const int c = plane % SEGC;
    const int im = plane / SEGC;
    const long base4 = (long)plane * HW4 + (long)bp * 4096;  // float4 units

    const float4* __restrict__ p4 = reinterpret_cast<const float4*>(pred);
    const float4* __restrict__ t4 = reinterpret_cast<const float4*>(annot);

    float sxy = 0.0f, sx0 = 0.0f, syv = 0.0f, foc = 0.0f;

    for (int i = 0; i < 4; ++i) {            // 4 chunks of 4 float4/thread
        float4 P[4], T[4];
        #pragma unroll
        for (int j = 0; j < 4; ++j) {
            const long idx = base4 + (long)(i * 1024 + j * 256 + threadIdx.x);
            P[j] = p4[idx];
            T[j] = t4[idx];
        }
        #pragma unroll
        for (int j = 0; j < 4; ++j) {
            const float px[4] = { P[j].x, P[j].y, P[j].z, P[j].w };
            const float tx[4] = { T[j].x, T[j].y, T[j].z, T[j].w };
            #pragma unroll
            for (int e = 0; e < 4; ++e) {
                const float x = px[e], y = tx[e];
                const bool sel = y > 0.5f;
                sxy = fmaf(x, y, sxy);
                sx0 = fmaf(x, 1.0f - y, sx0);
                syv += y;
                // focal: s=(2y-1)x; t=e^{-s}; logpt=log(1+t); 1-pt=t/(1+t)
                const float s = sel ? x : -x;
                const float t = __expf(-s);
                const float u = 1.0f + t;
                const float r = __builtin_amdgcn_rcpf(u);
                const float omp = t * r;
                const float logpt = __logf(u);
                const float w = sel ? 0.25f : 0.75f;
                foc += omp * omp * logpt * w;
            }
        }
    }

    double inter = (double)sxy, fpv = (double)sx0, ycv = (double)syv, fo = (double)foc;

    __shared__ double sred[4][4];
    const int wid = threadIdx.x >> 6, lane = threadIdx.x & 63;
    inter = waveRed(inter);
    fpv   = waveRed(fpv);
    ycv   = waveRed(ycv);
    fo    = waveRed(fo);
    if (lane == 0) { sred[0][wid] = inter; sred[1][wid] = fpv; sred[2][wid] = ycv; sred[3][wid] = fo; }
    __syncthreads();
    if (threadIdx.x == 0) {
        double a = 0, b2 = 0, cc = 0, dd = 0;
        for (int w = 0; w < 4; ++w) { a += sred[0][w]; b2 += sred[1][w]; cc += sred[2][w]; dd += sred[3][w]; }
        const int s = im * NBP + bp;         // 0..479
        double* seg_ws = ws + SEG_WS_OFF;
        seg_ws[(c * 4 + 0) * SEG_S + s] = a;
        seg_ws[(c * 4 + 1) * SEG_S + s] = b2;
        seg_ws[(c * 4 + 2) * SEG_S + s] = cc;
        seg_ws[(c * 4 + 3) * SEG_S + s] = dd;
    }
}

__global__ __launch_bounds__(1024) void fin_kernel(
    const double* __restrict__ ws, float* __restrict__ out)
{
    __shared__ double sseg[SEGC][4];   // [c][q]
    __shared__ double sdet[3][B_N];    // [q][b]

    const int t = threadIdx.x;

    // threads 0..767: 12 waves, one per (c,q) seg reduce over 480 partials
    if (t < 768) {
        const int w = t >> 6, lane = t & 63;
        const int c = w >> 2, q = w & 3;
        const double* base = ws + SEG_WS_OFF + (c * 4 + q) * SEG_S;
        double s = 0.0;
        #pragma unroll
        for (int i = 0; i < SEG_S / 64 + 1; ++i) {
            const int idx = i * 64 + lane;
            if (idx < SEG_S) s += base[idx];
        }
        s = waveRed(s);
        if (lane == 0) sseg[c][q] = s;
    } else if (t < 768 + 96) {
        // threads 768..863: det reduce, one thread per (q,b), 23 values each
        const int r = t - 768;
        const int q = r >> 5, b = r & 31;
        const double* base = ws + q * (B_N * ABLK) + b * ABLK;
        double s = 0.0;
        #pragma unroll
        for (int i = 0; i < ABLK; ++i) s += base[i];
        sdet[q][b] = s;
    }
    __syncthreads();

    if (t == 0) {
        double clsm = 0.0, regm = 0.0;
        for (int b = 0; b < B_N; ++b) {
            const double np_ = sdet[2][b];
            const double mnp = fmax(np_, 1.0);
            clsm += sdet[0][b] / mnp;
            regm += (np_ > 0.0) ? sdet[1][b] / (4.0 * mnp) : 0.0;
        }
        clsm /= (double)B_N;
        regm = regm / (double)B_N * 50.0;

        double tsum = 0.0;
        for (int c = 0; c < SEGC; ++c) {
            const double inter = sseg[c][0];
            const double fpv = sseg[c][1];
            const double ycnt = sseg[c][2];
            const double fnv = ycnt - inter;
            const double denom = fmax(inter + 0.7 * fpv + 0.3 * fnv, 1e-7);
            const double score = inter / denom;
            const double mask = (ycnt > 0.0) ? 1.0 : 0.0;
            tsum += (1.0 - score) * mask;
        }
        const double tv = pow(tsum / 3.0, 4.0 / 3.0);
        double focm = 0.0;
        for (int c = 0; c < SEGC; ++c) focm += sseg[c][3];
        focm /= (double)SEG_TOTAL;

        out[0] = (float)clsm;
        out[1] = (float)regm;
        out[2] = (float)(tv + focm);
    }
}

extern "C" void kernel_launch(void* const* d_in, const int* in_sizes, int n_in,
                              void* d_out, int out_size, void* d_ws, size_t ws_size,
                              hipStream_t stream) {
    const float* cls    = (const float*)d_in[0];  // [B,A,1]
    const float* reg    = (const float*)d_in[1];  // [B,A,4]
    const float* anc    = (const float*)d_in[2];  // [1,A,4]
    const float* ann    = (const float*)d_in[3];  // [B,M,5]
    const float* seg    = (const float*)d_in[4];  // [B,3,H,W]
    const float* segann = (const float*)d_in[5];  // [B,3,H,W]
    double* ws = (double*)d_ws;
    float* out = (float*)d_out;

    det_kernel<<<dim3(ABLK, B_N), 256, 0, stream>>>(cls, reg, anc, ann, ws);
    seg_kernel<<<SEG_BLOCKS, 256, 0, stream>>>(seg, segann, ws);
    fin_kernel<<<1, 1024, 0, stream>>>(ws, out);
}

// Round 4
// 84.860 us; speedup vs baseline: 3.4200x; 1.2363x over previous
//
#include <hip/hip_runtime.h>
#include <math.h>

#define A_N 46035
#define B_N 32
#define M_N 64
#define SEGC 3
#define HW 245760            // 384*640
#define HW4 61440            // HW/4
#define NBP 48               // seg blocks per plane
#define SEG_BLOCKS (B_N * SEGC * NBP)   // 4608
#define SEG_TOTAL 23592960   // B*SEGC*HW
#define DET_K 8              // anchors per thread
#define ABLK 23              // ceil(A_N / (256*DET_K))
#define DET_BLOCKS (ABLK * B_N)         // 736
#define F4_PER_BLOCK (HW4 / NBP)        // 1280
#define F4_PER_THREAD 5

// ws layout (doubles), all slots written unconditionally each call:
// det partials: [3][B_N][ABLK]  (q=0 cls, q=1 reg, q=2 pos)       = 2208
// seg partials: [SEGC][4][SEG_S] (q=0 inter, 1 fp, 2 ycnt, 3 foc) = 18432
#define DET_WS 2208
#define SEG_WS_OFF DET_WS
#define SEG_S (B_N * NBP)    // 1536 partials per (c,q)

__device__ __forceinline__ double waveRed(double v) {
    for (int o = 32; o; o >>= 1) v += __shfl_down(v, o, 64);
    return v;
}

__device__ __forceinline__ void det_path(
    int blk, const float* __restrict__ cls, const float* __restrict__ reg,
    const float* __restrict__ anc, const float* __restrict__ ann,
    double* __restrict__ ws)
{
    const int b = blk / ABLK;
    const int bx = blk % ABLK;
    const int tid = threadIdx.x;
    const int a_base = bx * (256 * DET_K) + tid;

    __shared__ float4 sbox[M_N];   // x1,y1,x2,y2
    __shared__ float2 sal[M_N];    // area, label
    if (tid < M_N) {
        const float* p = &ann[(b * M_N + tid) * 5];
        const float x1 = p[0], y1 = p[1], x2 = p[2], y2 = p[3], lb = p[4];
        sbox[tid] = make_float4(x1, y1, x2, y2);
        sal[tid] = make_float2((x2 - x1) * (y2 - y1), lb);
    }
    __syncthreads();

    float ax1[DET_K], ay1[DET_K], ax2[DET_K], ay2[DET_K], aarea[DET_K];
    float best[DET_K];
    int barg[DET_K];
    bool act[DET_K];

    #pragma unroll
    for (int k = 0; k < DET_K; ++k) {
        int a = a_base + k * 256;
        act[k] = a < A_N;
        const int al = act[k] ? a : (A_N - 1);
        const float4 av = *reinterpret_cast<const float4*>(&anc[al * 4]);
        ay1[k] = av.x; ax1[k] = av.y; ay2[k] = av.z; ax2[k] = av.w;
        aarea[k] = (av.z - av.x) * (av.w - av.y);
        best[k] = -__builtin_inff();
        barg[k] = 0;
    }

    #pragma unroll 2
    for (int m = 0; m < M_N; ++m) {
        const float4 bb = sbox[m];
        const float ba = sal[m].x;
        #pragma unroll
        for (int k = 0; k < DET_K; ++k) {
            const float iw = fminf(ax2[k], bb.z) - fmaxf(ax1[k], bb.x);
            const float ih = fminf(ay2[k], bb.w) - fmaxf(ay1[k], bb.y);
            const float inter = fmaxf(iw, 0.0f) * fmaxf(ih, 0.0f);
            const float ua = fmaxf(aarea[k] + ba - inter, 1e-8f);
            const float v = inter * __builtin_amdgcn_rcpf(ua);
            const bool upd = v > best[k];
            best[k] = upd ? v : best[k];
            barg[k] = upd ? m : barg[k];
        }
    }

    float cls_f = 0.0f, reg_f = 0.0f;
    int pos_i = 0;

    #pragma unroll
    for (int k = 0; k < DET_K; ++k) {
        if (!act[k]) continue;
        const int a = a_base + k * 256;
        const float4 g = sbox[barg[k]];
        const float2 al2 = sal[barg[k]];

        const bool big = al2.x > 100.0f;
        const bool pos = big ? (best[k] >= 0.5f) : (best[k] >= 0.15f);
        pos_i += pos ? 1 : 0;

        float p = cls[b * A_N + a];
        p = fminf(fmaxf(p, 1e-4f), 1.0f - 1e-4f);
        const bool t1 = pos && ((int)al2.y == 0);
        const float af = t1 ? 0.25f : 0.75f;
        const float fw = t1 ? (1.0f - p) : p;
        const float bce = t1 ? (-logf(p)) : (-logf(1.0f - p));
        cls_f += af * fw * fw * bce;

        if (pos) {
            const float aw = ax2[k] - ax1[k];
            const float ah = ay2[k] - ay1[k];
            const float acx = ax1[k] + 0.5f * aw;
            const float acy = ay1[k] + 0.5f * ah;
            const float gw0 = g.z - g.x;
            const float gh0 = g.w - g.y;
            const float gcx = g.x + 0.5f * gw0;   // centers from UNclamped sizes
            const float gcy = g.y + 0.5f * gh0;
            const float gw = fmaxf(gw0, 1.0f);
            const float gh = fmaxf(gh0, 1.0f);
            const float t0 = (gcy - acy) / ah;    // tdy
            const float t1r = (gcx - acx) / aw;   // tdx
            const float t2 = logf(gh / ah);       // tdh
            const float t3 = logf(gw / aw);       // tdw

            const float4 rv = *reinterpret_cast<const float4*>(&reg[(size_t)(b * A_N + a) * 4]);
            float d, rl, s = 0.0f;
            d = fabsf(t0 - rv.x);  rl = (d <= 1.0f/9.0f) ? 4.5f*d*d : d - 0.5f/9.0f; s += rl;
            d = fabsf(t1r - rv.y); rl = (d <= 1.0f/9.0f) ? 4.5f*d*d : d - 0.5f/9.0f; s += rl;
            d = fabsf(t2 - rv.z);  rl = (d <= 1.0f/9.0f) ? 4.5f*d*d : d - 0.5f/9.0f; s += rl;
            d = fabsf(t3 - rv.w);  rl = (d <= 1.0f/9.0f) ? 4.5f*d*d : d - 0.5f/9.0f; s += rl;
            reg_f += s;
        }
    }

    double cls_c = (double)cls_f, reg_c = (double)reg_f, pos_c = (double)pos_i;

    __shared__ double sredd[3][4];
    const int wid = threadIdx.x >> 6, lane = threadIdx.x & 63;
    cls_c = waveRed(cls_c);
    reg_c = waveRed(reg_c);
    pos_c = waveRed(pos_c);
    if (lane == 0) { sredd[0][wid] = cls_c; sredd[1][wid] = reg_c; sredd[2][wid] = pos_c; }
    __syncthreads();
    if (threadIdx.x == 0) {
        double c = 0, r = 0, pp = 0;
        for (int w = 0; w < 4; ++w) { c += sredd[0][w]; r += sredd[1][w]; pp += sredd[2][w]; }
        ws[0 * (B_N * ABLK) + b * ABLK + bx] = c;
        ws[1 * (B_N * ABLK) + b * ABLK + bx] = r;
        ws[2 * (B_N * ABLK) + b * ABLK + bx] = pp;
    }
}

__device__ __forceinline__ void seg_path(
    int sblk, const float* __restrict__ pred, const float* __restrict__ annot,
    double* __restrict__ ws)
{
    const int plane = sblk / NBP;            // 0..95 (wave-uniform)
    const int bp = sblk % NBP;
    const int c = plane % SEGC;
    const int im = plane / SEGC;
    const long base4 = (long)plane * HW4 + (long)bp * F4_PER_BLOCK;

    const float4* __restrict__ p4 = reinterpret_cast<const float4*>(pred);
    const float4* __restrict__ t4 = reinterpret_cast<const float4*>(annot);

    // one batch: 5 P + 5 T float4 loads, all outstanding together
    float4 P[F4_PER_THREAD], T[F4_PER_THREAD];
    #pragma unroll
    for (int j = 0; j < F4_PER_THREAD; ++j) {
        const long idx = base4 + (long)(j * 256 + threadIdx.x);
        P[j] = p4[idx];
        T[j] = t4[idx];
    }
    __builtin_amdgcn_sched_barrier(0);   // keep all 10 loads issued before compute

    float sxy = 0.0f, sx0 = 0.0f, syv = 0.0f, foc = 0.0f;
    #pragma unroll
    for (int j = 0; j < F4_PER_THREAD; ++j) {
        const float px[4] = { P[j].x, P[j].y, P[j].z, P[j].w };
        const float tx[4] = { T[j].x, T[j].y, T[j].z, T[j].w };
        #pragma unroll
        for (int e = 0; e < 4; ++e) {
            const float x = px[e], y = tx[e];
            const bool sel = y > 0.5f;
            sxy = fmaf(x, y, sxy);
            sx0 = fmaf(x, 1.0f - y, sx0);
            syv += y;
            // focal: s=(2y-1)x; t=e^{-s}; logpt=log(1+t); 1-pt=t/(1+t)
            const float s = sel ? x : -x;
            const float t = __expf(-s);
            const float u = 1.0f + t;
            const float r = __builtin_amdgcn_rcpf(u);
            const float omp = t * r;
            const float logpt = __logf(u);
            const float w = sel ? 0.25f : 0.75f;
            foc += omp * omp * logpt * w;
        }
    }

    double inter = (double)sxy, fpv = (double)sx0, ycv = (double)syv, fo = (double)foc;

    __shared__ double sreds[4][4];
    const int wid = threadIdx.x >> 6, lane = threadIdx.x & 63;
    inter = waveRed(inter);
    fpv   = waveRed(fpv);
    ycv   = waveRed(ycv);
    fo    = waveRed(fo);
    if (lane == 0) { sreds[0][wid] = inter; sreds[1][wid] = fpv; sreds[2][wid] = ycv; sreds[3][wid] = fo; }
    __syncthreads();
    if (threadIdx.x == 0) {
        double a = 0, b2 = 0, cc = 0, dd = 0;
        for (int w = 0; w < 4; ++w) { a += sreds[0][w]; b2 += sreds[1][w]; cc += sreds[2][w]; dd += sreds[3][w]; }
        const int s = im * NBP + bp;         // 0..1535
        double* seg_ws = ws + SEG_WS_OFF;
        seg_ws[(c * 4 + 0) * SEG_S + s] = a;
        seg_ws[(c * 4 + 1) * SEG_S + s] = b2;
        seg_ws[(c * 4 + 2) * SEG_S + s] = cc;
        seg_ws[(c * 4 + 3) * SEG_S + s] = dd;
    }
}

__global__ __launch_bounds__(256) void fused_kernel(
    const float* __restrict__ cls, const float* __restrict__ reg,
    const float* __restrict__ anc, const float* __restrict__ ann,
    const float* __restrict__ pred, const float* __restrict__ annot,
    double* __restrict__ ws)
{
    const int blk = blockIdx.x;
    if (blk < DET_BLOCKS) {
        det_path(blk, cls, reg, anc, ann, ws);
    } else {
        seg_path(blk - DET_BLOCKS, pred, annot, ws);
    }
}

__global__ __launch_bounds__(1024) void fin_kernel(
    const double* __restrict__ ws, float* __restrict__ out)
{
    __shared__ double sseg[SEGC][4];   // [c][q]
    __shared__ double sdet[3][B_N];    // [q][b]

    const int t = threadIdx.x;

    // threads 0..767: 12 waves, one per (c,q) seg reduce over 1536 partials
    if (t < 768) {
        const int w = t >> 6, lane = t & 63;
        const int c = w >> 2, q = w & 3;
        const double* base = ws + SEG_WS_OFF + (c * 4 + q) * SEG_S;
        double s = 0.0;
        #pragma unroll
        for (int i = 0; i < SEG_S / 64; ++i)
            s += base[i * 64 + lane];
        s = waveRed(s);
        if (lane == 0) sseg[c][q] = s;
    } else if (t < 768 + 96) {
        // threads 768..863: det reduce, one thread per (q,b), 23 values each
        const int r = t - 768;
        const int q = r >> 5, b = r & 31;
        const double* base = ws + q * (B_N * ABLK) + b * ABLK;
        double s = 0.0;
        #pragma unroll
        for (int i = 0; i < ABLK; ++i) s += base[i];
        sdet[q][b] = s;
    }
    __syncthreads();

    if (t == 0) {
        double clsm = 0.0, regm = 0.0;
        for (int b = 0; b < B_N; ++b) {
            const double np_ = sdet[2][b];
            const double mnp = fmax(np_, 1.0);
            clsm += sdet[0][b] / mnp;
            regm += (np_ > 0.0) ? sdet[1][b] / (4.0 * mnp) : 0.0;
        }
        clsm /= (double)B_N;
        regm = regm / (double)B_N * 50.0;

        double tsum = 0.0;
        for (int c = 0; c < SEGC; ++c) {
            const double inter = sseg[c][0];
            const double fpv = sseg[c][1];
            const double ycnt = sseg[c][2];
            const double fnv = ycnt - inter;
            const double denom = fmax(inter + 0.7 * fpv + 0.3 * fnv, 1e-7);
            const double score = inter / denom;
            const double mask = (ycnt > 0.0) ? 1.0 : 0.0;
            tsum += (1.0 - score) * mask;
        }
        const double tv = pow(tsum / 3.0, 4.0 / 3.0);
        double focm = 0.0;
        for (int c = 0; c < SEGC; ++c) focm += sseg[c][3];
        focm /= (double)SEG_TOTAL;

        out[0] = (float)clsm;
        out[1] = (float)regm;
        out[2] = (float)(tv + focm);
    }
}

extern "C" void kernel_launch(void* const* d_in, const int* in_sizes, int n_in,
                              void* d_out, int out_size, void* d_ws, size_t ws_size,
                              hipStream_t stream) {
    const float* cls    = (const float*)d_in[0];  // [B,A,1]
    const float* reg    = (const float*)d_in[1];  // [B,A,4]
    const float* anc    = (const float*)d_in[2];  // [1,A,4]
    const float* ann    = (const float*)d_in[3];  // [B,M,5]
    const float* seg    = (const float*)d_in[4];  // [B,3,H,W]
    const float* segann = (const float*)d_in[5];  // [B,3,H,W]
    double* ws = (double*)d_ws;
    float* out = (float*)d_out;

    fused_kernel<<<DET_BLOCKS + SEG_BLOCKS, 256, 0, stream>>>(
        cls, reg, anc, ann, seg, segann, ws);
    fin_kernel<<<1, 1024, 0, stream>>>(ws, out);
}

// Round 5
// 68.791 us; speedup vs baseline: 4.2188x; 1.2336x over previous
//
#include <hip/hip_runtime.h>
#include <math.h>

#define A_N 46035
#define B_N 32
#define M_N 64
#define SEGC 3
#define HW 245760            // 384*640
#define HW4 61440            // HW/4
#define NBP 48               // seg blocks per plane
#define SEG_BLOCKS (B_N * SEGC * NBP)   // 4608
#define SEG_TOTAL 23592960   // B*SEGC*HW
#define DET_K 8              // anchors per thread
#define ABLK 23              // ceil(A_N / (256*DET_K))
#define DET_BLOCKS (ABLK * B_N)         // 736
#define F4_PER_BLOCK (HW4 / NBP)        // 1280
#define F4_PER_THREAD 5

// ws layout (doubles), all slots written unconditionally each call:
// det partials: [3][B_N][ABLK]  (q=0 cls, q=1 reg, q=2 pos)       = 2208
// seg partials: [SEGC][4][SEG_S] (q=0 inter, 1 sum_x, 2 sum_y, 3 foc)
#define DET_WS 2208
#define SEG_WS_OFF DET_WS
#define SEG_S (B_N * NBP)    // 1536 partials per (c,q)

__device__ __forceinline__ double waveRed(double v) {
    for (int o = 32; o; o >>= 1) v += __shfl_down(v, o, 64);
    return v;
}

__device__ __forceinline__ void det_path(
    int blk, const float* __restrict__ cls, const float* __restrict__ reg,
    const float* __restrict__ anc, const float* __restrict__ ann,
    double* __restrict__ ws)
{
    const int b = blk / ABLK;
    const int bx = blk % ABLK;
    const int tid = threadIdx.x;
    const int a_base = bx * (256 * DET_K) + tid;

    __shared__ float4 sbox[M_N];   // x1,y1,x2,y2
    __shared__ float2 sal[M_N];    // area, label
    __shared__ int smv;
    if (tid < M_N) {
        const float* p = &ann[(b * M_N + tid) * 5];
        const float x1 = p[0], y1 = p[1], x2 = p[2], y2 = p[3], lb = p[4];
        sbox[tid] = make_float4(x1, y1, x2, y2);
        sal[tid] = make_float2((x2 - x1) * (y2 - y1), lb);
        // valid boxes are a -1-padded prefix; count them (invalid can never win argmax)
        unsigned long long vm = __ballot(lb != -1.0f);
        if (tid == 0) smv = (int)__popcll(vm);
    }
    __syncthreads();
    const int mv = smv;

    float ax1[DET_K], ay1[DET_K], ax2[DET_K], ay2[DET_K], aarea[DET_K];
    float binter[DET_K], bua[DET_K], pc[DET_K];
    int barg[DET_K];
    bool act[DET_K];

    #pragma unroll
    for (int k = 0; k < DET_K; ++k) {
        int a = a_base + k * 256;
        act[k] = a < A_N;
        const int al = act[k] ? a : (A_N - 1);
        const float4 av = *reinterpret_cast<const float4*>(&anc[al * 4]);
        ay1[k] = av.x; ax1[k] = av.y; ay2[k] = av.z; ax2[k] = av.w;
        aarea[k] = (av.z - av.x) * (av.w - av.y);
        binter[k] = -1.0f;   // first m always updates: rhs = -ua < 0 <= lhs
        bua[k] = 1.0f;
        barg[k] = 0;
        pc[k] = cls[b * A_N + al];   // prefetch, hides under IoU loop
    }

    #pragma unroll 4
    for (int m = 0; m < mv; ++m) {
        const float4 bb = sbox[m];
        const float ba = sal[m].x;
        #pragma unroll
        for (int k = 0; k < DET_K; ++k) {
            const float iw = fmaxf(fminf(ax2[k], bb.z) - fmaxf(ax1[k], bb.x), 0.0f);
            const float ih = fmaxf(fminf(ay2[k], bb.w) - fmaxf(ay1[k], bb.y), 0.0f);
            const float inter = iw * ih;
            const float ua = (aarea[k] + ba) - inter;   // > 0 always (aarea > 64)
            // inter/ua > binter/bua  <=>  inter*bua > binter*ua  (ua,bua > 0)
            const bool upd = inter * bua[k] > binter[k] * ua;
            binter[k] = upd ? inter : binter[k];
            bua[k]    = upd ? ua    : bua[k];
            barg[k]   = upd ? m     : barg[k];
        }
    }

    float cls_f = 0.0f, reg_f = 0.0f;
    int pos_i = 0;

    #pragma unroll
    for (int k = 0; k < DET_K; ++k) {
        if (!act[k]) continue;
        const int a = a_base + k * 256;
        const float4 g = sbox[barg[k]];
        const float2 al2 = sal[barg[k]];

        const bool big = al2.x > 100.0f;
        const float thr = big ? 0.5f : 0.15f;
        const bool pos = binter[k] >= thr * bua[k];   // best >= thr, division-free
        pos_i += pos ? 1 : 0;

        float p = pc[k];
        p = fminf(fmaxf(p, 1e-4f), 1.0f - 1e-4f);
        const bool t1 = pos && ((int)al2.y == 0);
        const float af = t1 ? 0.25f : 0.75f;
        const float fw = t1 ? (1.0f - p) : p;
        const float bce = t1 ? (-logf(p)) : (-logf(1.0f - p));
        cls_f += af * fw * fw * bce;

        if (pos) {
            const float aw = ax2[k] - ax1[k];
            const float ah = ay2[k] - ay1[k];
            const float acx = ax1[k] + 0.5f * aw;
            const float acy = ay1[k] + 0.5f * ah;
            const float gw0 = g.z - g.x;
            const float gh0 = g.w - g.y;
            const float gcx = g.x + 0.5f * gw0;   // centers from UNclamped sizes
            const float gcy = g.y + 0.5f * gh0;
            const float gw = fmaxf(gw0, 1.0f);
            const float gh = fmaxf(gh0, 1.0f);
            const float t0 = (gcy - acy) / ah;    // tdy
            const float t1r = (gcx - acx) / aw;   // tdx
            const float t2 = logf(gh / ah);       // tdh
            const float t3 = logf(gw / aw);       // tdw

            const float4 rv = *reinterpret_cast<const float4*>(&reg[(size_t)(b * A_N + a) * 4]);
            float d, rl, s = 0.0f;
            d = fabsf(t0 - rv.x);  rl = (d <= 1.0f/9.0f) ? 4.5f*d*d : d - 0.5f/9.0f; s += rl;
            d = fabsf(t1r - rv.y); rl = (d <= 1.0f/9.0f) ? 4.5f*d*d : d - 0.5f/9.0f; s += rl;
            d = fabsf(t2 - rv.z);  rl = (d <= 1.0f/9.0f) ? 4.5f*d*d : d - 0.5f/9.0f; s += rl;
            d = fabsf(t3 - rv.w);  rl = (d <= 1.0f/9.0f) ? 4.5f*d*d : d - 0.5f/9.0f; s += rl;
            reg_f += s;
        }
    }

    double cls_c = (double)cls_f, reg_c = (double)reg_f, pos_c = (double)pos_i;

    __shared__ double sredd[3][4];
    const int wid = threadIdx.x >> 6, lane = threadIdx.x & 63;
    cls_c = waveRed(cls_c);
    reg_c = waveRed(reg_c);
    pos_c = waveRed(pos_c);
    if (lane == 0) { sredd[0][wid] = cls_c; sredd[1][wid] = reg_c; sredd[2][wid] = pos_c; }
    __syncthreads();
    if (threadIdx.x == 0) {
        double c = 0, r = 0, pp = 0;
        for (int w = 0; w < 4; ++w) { c += sredd[0][w]; r += sredd[1][w]; pp += sredd[2][w]; }
        ws[0 * (B_N * ABLK) + b * ABLK + bx] = c;
        ws[1 * (B_N * ABLK) + b * ABLK + bx] = r;
        ws[2 * (B_N * ABLK) + b * ABLK + bx] = pp;
    }
}

__device__ __forceinline__ void seg_path(
    int sblk, const float* __restrict__ pred, const float* __restrict__ annot,
    double* __restrict__ ws)
{
    const int plane = sblk / NBP;            // 0..95 (wave-uniform)
    const int bp = sblk % NBP;
    const int c = plane % SEGC;
    const int im = plane / SEGC;
    const long base4 = (long)plane * HW4 + (long)bp * F4_PER_BLOCK;

    const float4* __restrict__ p4 = reinterpret_cast<const float4*>(pred);
    const float4* __restrict__ t4 = reinterpret_cast<const float4*>(annot);

    // one batch: 5 P + 5 T float4 loads, all outstanding together
    float4 P[F4_PER_THREAD], T[F4_PER_THREAD];
    #pragma unroll
    for (int j = 0; j < F4_PER_THREAD; ++j) {
        const long idx = base4 + (long)(j * 256 + threadIdx.x);
        P[j] = p4[idx];
        T[j] = t4[idx];
    }
    __builtin_amdgcn_sched_barrier(0);   // keep all 10 loads issued before compute

    float sxy = 0.0f, sx = 0.0f, syv = 0.0f, foc = 0.0f;
    #pragma unroll
    for (int j = 0; j < F4_PER_THREAD; ++j) {
        const float px[4] = { P[j].x, P[j].y, P[j].z, P[j].w };
        const float tx[4] = { T[j].x, T[j].y, T[j].z, T[j].w };
        #pragma unroll
        for (int e = 0; e < 4; ++e) {
            const float x = px[e], y = tx[e];
            const bool sel = y > 0.5f;
            sxy = fmaf(x, y, sxy);
            sx += x;                       // fp = sum_x - inter, in finalize
            syv += y;
            // focal: s=(2y-1)x; t=e^{-s}; logpt=log(1+t); 1-pt=t/(1+t)
            const float s = sel ? x : -x;
            const float t = __expf(-s);
            const float u = 1.0f + t;
            const float r = __builtin_amdgcn_rcpf(u);
            const float omp = t * r;
            const float logpt = __logf(u);
            const float w = fmaf(y, -0.5f, 0.75f);   // 0.25*y + 0.75*(1-y)
            foc = fmaf(omp * omp * logpt, w, foc);
        }
    }

    double inter = (double)sxy, sxd = (double)sx, ycv = (double)syv, fo = (double)foc;

    __shared__ double sreds[4][4];
    const int wid = threadIdx.x >> 6, lane = threadIdx.x & 63;
    inter = waveRed(inter);
    sxd   = waveRed(sxd);
    ycv   = waveRed(ycv);
    fo    = waveRed(fo);
    if (lane == 0) { sreds[0][wid] = inter; sreds[1][wid] = sxd; sreds[2][wid] = ycv; sreds[3][wid] = fo; }
    __syncthreads();
    if (threadIdx.x == 0) {
        double a = 0, b2 = 0, cc = 0, dd = 0;
        for (int w = 0; w < 4; ++w) { a += sreds[0][w]; b2 += sreds[1][w]; cc += sreds[2][w]; dd += sreds[3][w]; }
        const int s = im * NBP + bp;         // 0..1535
        double* seg_ws = ws + SEG_WS_OFF;
        seg_ws[(c * 4 + 0) * SEG_S + s] = a;
        seg_ws[(c * 4 + 1) * SEG_S + s] = b2;
        seg_ws[(c * 4 + 2) * SEG_S + s] = cc;
        seg_ws[(c * 4 + 3) * SEG_S + s] = dd;
    }
}

__global__ __launch_bounds__(256) void fused_kernel(
    const float* __restrict__ cls, const float* __restrict__ reg,
    const float* __restrict__ anc, const float* __restrict__ ann,
    const float* __restrict__ pred, const float* __restrict__ annot,
    double* __restrict__ ws)
{
    const int blk = blockIdx.x;
    if (blk < DET_BLOCKS) {
        det_path(blk, cls, reg, anc, ann, ws);
    } else {
        seg_path(blk - DET_BLOCKS, pred, annot, ws);
    }
}

__global__ __launch_bounds__(1024) void fin_kernel(
    const double* __restrict__ ws, float* __restrict__ out)
{
    __shared__ double sseg[SEGC][4];   // [c][q]
    __shared__ double sdet[3][B_N];    // [q][b]

    const int t = threadIdx.x;

    // threads 0..767: 12 waves, one per (c,q) seg reduce over 1536 partials
    if (t < 768) {
        const int w = t >> 6, lane = t & 63;
        const int c = w >> 2, q = w & 3;
        const double* base = ws + SEG_WS_OFF + (c * 4 + q) * SEG_S;
        double s = 0.0;
        #pragma unroll
        for (int i = 0; i < SEG_S / 64; ++i)
            s += base[i * 64 + lane];
        s = waveRed(s);
        if (lane == 0) sseg[c][q] = s;
    } else if (t < 768 + 96) {
        // threads 768..863: det reduce, one thread per (q,b), 23 values each
        const int r = t - 768;
        const int q = r >> 5, b = r & 31;
        const double* base = ws + q * (B_N * ABLK) + b * ABLK;
        double s = 0.0;
        #pragma unroll
        for (int i = 0; i < ABLK; ++i) s += base[i];
        sdet[q][b] = s;
    }
    __syncthreads();

    if (t == 0) {
        double clsm = 0.0, regm = 0.0;
        for (int b = 0; b < B_N; ++b) {
            const double np_ = sdet[2][b];
            const double mnp = fmax(np_, 1.0);
            clsm += sdet[0][b] / mnp;
            regm += (np_ > 0.0) ? sdet[1][b] / (4.0 * mnp) : 0.0;
        }
        clsm /= (double)B_N;
        regm = regm / (double)B_N * 50.0;

        double tsum = 0.0;
        for (int c = 0; c < SEGC; ++c) {
            const double inter = sseg[c][0];
            const double fpv = sseg[c][1] - inter;     // sum_x - inter
            const double ycnt = sseg[c][2];
            const double fnv = ycnt - inter;
            const double denom = fmax(inter + 0.7 * fpv + 0.3 * fnv, 1e-7);
            const double score = inter / denom;
            const double mask = (ycnt > 0.0) ? 1.0 : 0.0;
            tsum += (1.0 - score) * mask;
        }
        const double tv = pow(tsum / 3.0, 4.0 / 3.0);
        double focm = 0.0;
        for (int c = 0; c < SEGC; ++c) focm += sseg[c][3];
        focm /= (double)SEG_TOTAL;

        out[0] = (float)clsm;
        out[1] = (float)regm;
        out[2] = (float)(tv + focm);
    }
}

extern "C" void kernel_launch(void* const* d_in, const int* in_sizes, int n_in,
                              void* d_out, int out_size, void* d_ws, size_t ws_size,
                              hipStream_t stream) {
    const float* cls    = (const float*)d_in[0];  // [B,A,1]
    const float* reg    = (const float*)d_in[1];  // [B,A,4]
    const float* anc    = (const float*)d_in[2];  // [1,A,4]
    const float* ann    = (const float*)d_in[3];  // [B,M,5]
    const float* seg    = (const float*)d_in[4];  // [B,3,H,W]
    const float* segann = (const float*)d_in[5];  // [B,3,H,W]
    double* ws = (double*)d_ws;
    float* out = (float*)d_out;

    fused_kernel<<<DET_BLOCKS + SEG_BLOCKS, 256, 0, stream>>>(
        cls, reg, anc, ann, seg, segann, ws);
    fin_kernel<<<1, 1024, 0, stream>>>(ws, out);
}

// Round 6
// 65.819 us; speedup vs baseline: 4.4093x; 1.0451x over previous
//
#include <hip/hip_runtime.h>
#include <math.h>

#define A_N 46035
#define B_N 32
#define M_N 64
#define SEGC 3
#define HW 245760            // 384*640
#define HW4 61440            // HW/4
#define NBP 60               // seg blocks per plane
#define SEG_BLOCKS (B_N * SEGC * NBP)   // 5760
#define SEG_TOTAL 23592960   // B*SEGC*HW
#define DET_K 4              // anchors per thread
#define ABLK 45              // ceil(A_N / (256*DET_K))
#define DET_BLOCKS (ABLK * B_N)         // 1440
#define F4_PER_BLOCK (HW4 / NBP)        // 1024
#define F4_PER_THREAD 4

// ws layout (doubles), all slots written unconditionally each call:
// det partials: [3][B_N][ABLK]  (q=0 cls, q=1 reg, q=2 pos)       = 4320
// seg partials: [SEGC][4][SEG_S] (q=0 inter, 1 sum_x, 2 sum_y, 3 foc)
#define DET_WS (3 * B_N * ABLK)
#define SEG_WS_OFF DET_WS
#define SEG_S (B_N * NBP)    // 1920 partials per (c,q)

__device__ __forceinline__ double waveRed(double v) {
    for (int o = 32; o; o >>= 1) v += __shfl_down(v, o, 64);
    return v;
}

__device__ __forceinline__ void det_path(
    int blk, const float* __restrict__ cls, const float* __restrict__ reg,
    const float* __restrict__ anc, const float* __restrict__ ann,
    double* __restrict__ ws)
{
    const int b = blk / ABLK;
    const int bx = blk % ABLK;
    const int tid = threadIdx.x;
    const int a_base = bx * (256 * DET_K) + tid;

    __shared__ float4 sbox[M_N];   // x1,y1,x2,y2
    __shared__ float2 sal[M_N];    // area, label
    __shared__ int smv;
    if (tid < M_N) {
        const float* p = &ann[(b * M_N + tid) * 5];
        const float x1 = p[0], y1 = p[1], x2 = p[2], y2 = p[3], lb = p[4];
        sbox[tid] = make_float4(x1, y1, x2, y2);
        sal[tid] = make_float2((x2 - x1) * (y2 - y1), lb);
        // valid boxes are a -1-padded prefix; count them (invalid can never win argmax)
        unsigned long long vm = __ballot(lb != -1.0f);
        if (tid == 0) smv = (int)__popcll(vm);
    }
    __syncthreads();
    const int mv = smv;

    float ax1[DET_K], ay1[DET_K], ax2[DET_K], ay2[DET_K], aarea[DET_K];
    float binter[DET_K], bua[DET_K], pc[DET_K];
    int barg[DET_K];
    bool act[DET_K];

    #pragma unroll
    for (int k = 0; k < DET_K; ++k) {
        int a = a_base + k * 256;
        act[k] = a < A_N;
        const int al = act[k] ? a : (A_N - 1);
        const float4 av = *reinterpret_cast<const float4*>(&anc[al * 4]);
        ay1[k] = av.x; ax1[k] = av.y; ay2[k] = av.z; ax2[k] = av.w;
        aarea[k] = (av.z - av.x) * (av.w - av.y);
        binter[k] = -1.0f;   // first m always updates: rhs = -ua < 0 <= lhs
        bua[k] = 1.0f;
        barg[k] = 0;
        pc[k] = cls[b * A_N + al];   // prefetch, hides under IoU loop
    }

    #pragma unroll 4
    for (int m = 0; m < mv; ++m) {
        const float4 bb = sbox[m];
        const float ba = sal[m].x;
        #pragma unroll
        for (int k = 0; k < DET_K; ++k) {
            const float iw = fmaxf(fminf(ax2[k], bb.z) - fmaxf(ax1[k], bb.x), 0.0f);
            const float ih = fmaxf(fminf(ay2[k], bb.w) - fmaxf(ay1[k], bb.y), 0.0f);
            const float inter = iw * ih;
            const float ua = (aarea[k] + ba) - inter;   // > 0 always (aarea > 64)
            // inter/ua > binter/bua  <=>  inter*bua > binter*ua  (ua,bua > 0)
            const bool upd = inter * bua[k] > binter[k] * ua;
            binter[k] = upd ? inter : binter[k];
            bua[k]    = upd ? ua    : bua[k];
            barg[k]   = upd ? m     : barg[k];
        }
    }

    float cls_f = 0.0f, reg_f = 0.0f;
    int pos_i = 0;

    #pragma unroll
    for (int k = 0; k < DET_K; ++k) {
        if (!act[k]) continue;
        const int a = a_base + k * 256;
        const float4 g = sbox[barg[k]];
        const float2 al2 = sal[barg[k]];

        const bool big = al2.x > 100.0f;
        const float thr = big ? 0.5f : 0.15f;
        const bool pos = binter[k] >= thr * bua[k];   // best >= thr, division-free
        pos_i += pos ? 1 : 0;

        float p = pc[k];
        p = fminf(fmaxf(p, 1e-4f), 1.0f - 1e-4f);
        const bool t1 = pos && ((int)al2.y == 0);
        const float af = t1 ? 0.25f : 0.75f;
        const float fw = t1 ? (1.0f - p) : p;
        const float bce = t1 ? (-logf(p)) : (-logf(1.0f - p));
        cls_f += af * fw * fw * bce;

        if (pos) {
            const float aw = ax2[k] - ax1[k];
            const float ah = ay2[k] - ay1[k];
            const float acx = ax1[k] + 0.5f * aw;
            const float acy = ay1[k] + 0.5f * ah;
            const float gw0 = g.z - g.x;
            const float gh0 = g.w - g.y;
            const float gcx = g.x + 0.5f * gw0;   // centers from UNclamped sizes
            const float gcy = g.y + 0.5f * gh0;
            const float gw = fmaxf(gw0, 1.0f);
            const float gh = fmaxf(gh0, 1.0f);
            const float t0 = (gcy - acy) / ah;    // tdy
            const float t1r = (gcx - acx) / aw;   // tdx
            const float t2 = logf(gh / ah);       // tdh
            const float t3 = logf(gw / aw);       // tdw

            const float4 rv = *reinterpret_cast<const float4*>(&reg[(size_t)(b * A_N + a) * 4]);
            float d, rl, s = 0.0f;
            d = fabsf(t0 - rv.x);  rl = (d <= 1.0f/9.0f) ? 4.5f*d*d : d - 0.5f/9.0f; s += rl;
            d = fabsf(t1r - rv.y); rl = (d <= 1.0f/9.0f) ? 4.5f*d*d : d - 0.5f/9.0f; s += rl;
            d = fabsf(t2 - rv.z);  rl = (d <= 1.0f/9.0f) ? 4.5f*d*d : d - 0.5f/9.0f; s += rl;
            d = fabsf(t3 - rv.w);  rl = (d <= 1.0f/9.0f) ? 4.5f*d*d : d - 0.5f/9.0f; s += rl;
            reg_f += s;
        }
    }

    double cls_c = (double)cls_f, reg_c = (double)reg_f, pos_c = (double)pos_i;

    __shared__ double sredd[3][4];
    const int wid = threadIdx.x >> 6, lane = threadIdx.x & 63;
    cls_c = waveRed(cls_c);
    reg_c = waveRed(reg_c);
    pos_c = waveRed(pos_c);
    if (lane == 0) { sredd[0][wid] = cls_c; sredd[1][wid] = reg_c; sredd[2][wid] = pos_c; }
    __syncthreads();
    if (threadIdx.x == 0) {
        double c = 0, r = 0, pp = 0;
        for (int w = 0; w < 4; ++w) { c += sredd[0][w]; r += sredd[1][w]; pp += sredd[2][w]; }
        ws[0 * (B_N * ABLK) + b * ABLK + bx] = c;
        ws[1 * (B_N * ABLK) + b * ABLK + bx] = r;
        ws[2 * (B_N * ABLK) + b * ABLK + bx] = pp;
    }
}

__device__ __forceinline__ void seg_path(
    int sblk, const float* __restrict__ pred, const float* __restrict__ annot,
    double* __restrict__ ws)
{
    const int plane = sblk / NBP;            // 0..95 (wave-uniform)
    const int bp = sblk % NBP;
    const int c = plane % SEGC;
    const int im = plane / SEGC;
    const long base4 = (long)plane * HW4 + (long)bp * F4_PER_BLOCK;

    const float4* __restrict__ p4 = reinterpret_cast<const float4*>(pred);
    const float4* __restrict__ t4 = reinterpret_cast<const float4*>(annot);

    // one batch: 4 P + 4 T float4 loads, all outstanding together
    float4 P[F4_PER_THREAD], T[F4_PER_THREAD];
    #pragma unroll
    for (int j = 0; j < F4_PER_THREAD; ++j) {
        const long idx = base4 + (long)(j * 256 + threadIdx.x);
        P[j] = p4[idx];
        T[j] = t4[idx];
    }
    __builtin_amdgcn_sched_barrier(0);   // keep all 8 loads issued before compute

    float sxy = 0.0f, sx = 0.0f, syv = 0.0f, foc = 0.0f;
    #pragma unroll
    for (int j = 0; j < F4_PER_THREAD; ++j) {
        const float px[4] = { P[j].x, P[j].y, P[j].z, P[j].w };
        const float tx[4] = { T[j].x, T[j].y, T[j].z, T[j].w };
        #pragma unroll
        for (int e = 0; e < 4; ++e) {
            const float x = px[e], y = tx[e];
            const bool sel = y > 0.5f;
            sxy = fmaf(x, y, sxy);
            sx += x;                       // fp = sum_x - inter, in finalize
            syv += y;
            // focal: s=(2y-1)x; t=e^{-s}; logpt=log(1+t); 1-pt=t/(1+t)
            const float s = sel ? x : -x;
            const float t = __expf(-s);
            const float u = 1.0f + t;
            const float r = __builtin_amdgcn_rcpf(u);
            const float omp = t * r;
            const float logpt = __logf(u);
            const float w = fmaf(y, -0.5f, 0.75f);   // 0.25*y + 0.75*(1-y)
            foc = fmaf(omp * omp * logpt, w, foc);
        }
    }

    double inter = (double)sxy, sxd = (double)sx, ycv = (double)syv, fo = (double)foc;

    __shared__ double sreds[4][4];
    const int wid = threadIdx.x >> 6, lane = threadIdx.x & 63;
    inter = waveRed(inter);
    sxd   = waveRed(sxd);
    ycv   = waveRed(ycv);
    fo    = waveRed(fo);
    if (lane == 0) { sreds[0][wid] = inter; sreds[1][wid] = sxd; sreds[2][wid] = ycv; sreds[3][wid] = fo; }
    __syncthreads();
    if (threadIdx.x == 0) {
        double a = 0, b2 = 0, cc = 0, dd = 0;
        for (int w = 0; w < 4; ++w) { a += sreds[0][w]; b2 += sreds[1][w]; cc += sreds[2][w]; dd += sreds[3][w]; }
        const int s = im * NBP + bp;         // 0..1919
        double* seg_ws = ws + SEG_WS_OFF;
        seg_ws[(c * 4 + 0) * SEG_S + s] = a;
        seg_ws[(c * 4 + 1) * SEG_S + s] = b2;
        seg_ws[(c * 4 + 2) * SEG_S + s] = cc;
        seg_ws[(c * 4 + 3) * SEG_S + s] = dd;
    }
}

__global__ __launch_bounds__(256, 8) void fused_kernel(
    const float* __restrict__ cls, const float* __restrict__ reg,
    const float* __restrict__ anc, const float* __restrict__ ann,
    const float* __restrict__ pred, const float* __restrict__ annot,
    double* __restrict__ ws)
{
    const int blk = blockIdx.x;
    if (blk < DET_BLOCKS) {
        det_path(blk, cls, reg, anc, ann, ws);
    } else {
        seg_path(blk - DET_BLOCKS, pred, annot, ws);
    }
}

__global__ __launch_bounds__(1024) void fin_kernel(
    const double* __restrict__ ws, float* __restrict__ out)
{
    __shared__ double sseg[SEGC][4];   // [c][q]
    __shared__ double sdet[3][B_N];    // [q][b]

    const int t = threadIdx.x;

    // threads 0..767: 12 waves, one per (c,q) seg reduce over 1920 partials
    if (t < 768) {
        const int w = t >> 6, lane = t & 63;
        const int c = w >> 2, q = w & 3;
        const double* base = ws + SEG_WS_OFF + (c * 4 + q) * SEG_S;
        double s = 0.0;
        #pragma unroll
        for (int i = 0; i < SEG_S / 64; ++i)
            s += base[i * 64 + lane];
        s = waveRed(s);
        if (lane == 0) sseg[c][q] = s;
    } else if (t < 768 + 96) {
        // threads 768..863: det reduce, one thread per (q,b), ABLK values each
        const int r = t - 768;
        const int q = r >> 5, b = r & 31;
        const double* base = ws + q * (B_N * ABLK) + b * ABLK;
        double s = 0.0;
        #pragma unroll
        for (int i = 0; i < ABLK; ++i) s += base[i];
        sdet[q][b] = s;
    }
    __syncthreads();

    if (t == 0) {
        double clsm = 0.0, regm = 0.0;
        for (int b = 0; b < B_N; ++b) {
            const double np_ = sdet[2][b];
            const double mnp = fmax(np_, 1.0);
            clsm += sdet[0][b] / mnp;
            regm += (np_ > 0.0) ? sdet[1][b] / (4.0 * mnp) : 0.0;
        }
        clsm /= (double)B_N;
        regm = regm / (double)B_N * 50.0;

        double tsum = 0.0;
        for (int c = 0; c < SEGC; ++c) {
            const double inter = sseg[c][0];
            const double fpv = sseg[c][1] - inter;     // sum_x - inter
            const double ycnt = sseg[c][2];
            const double fnv = ycnt - inter;
            const double denom = fmax(inter + 0.7 * fpv + 0.3 * fnv, 1e-7);
            const double score = inter / denom;
            const double mask = (ycnt > 0.0) ? 1.0 : 0.0;
            tsum += (1.0 - score) * mask;
        }
        const double tv = pow(tsum / 3.0, 4.0 / 3.0);
        double focm = 0.0;
        for (int c = 0; c < SEGC; ++c) focm += sseg[c][3];
        focm /= (double)SEG_TOTAL;

        out[0] = (float)clsm;
        out[1] = (float)regm;
        out[2] = (float)(tv + focm);
    }
}

extern "C" void kernel_launch(void* const* d_in, const int* in_sizes, int n_in,
                              void* d_out, int out_size, void* d_ws, size_t ws_size,
                              hipStream_t stream) {
    const float* cls    = (const float*)d_in[0];  // [B,A,1]
    const float* reg    = (const float*)d_in[1];  // [B,A,4]
    const float* anc    = (const float*)d_in[2];  // [1,A,4]
    const float* ann    = (const float*)d_in[3];  // [B,M,5]
    const float* seg    = (const float*)d_in[4];  // [B,3,H,W]
    const float* segann = (const float*)d_in[5];  // [B,3,H,W]
    double* ws = (double*)d_ws;
    float* out = (float*)d_out;

    fused_kernel<<<DET_BLOCKS + SEG_BLOCKS, 256, 0, stream>>>(
        cls, reg, anc, ann, seg, segann, ws);
    fin_kernel<<<1, 1024, 0, stream>>>(ws, out);
}